// Round 11
// baseline (243.145 us; speedup 1.0000x reference)
//
#include <hip/hip_runtime.h>

#define BATCH 16
#define SEQ   2048
#define DIM   64
#define NTHREADS 256
#define NROWS    (BATCH * SEQ)      // 32768
#define OUTELEMS (NROWS * DIM)      // 2097152

typedef short bf16x8 __attribute__((ext_vector_type(8)));
typedef float f32x4 __attribute__((ext_vector_type(4)));

// LDS row offset (shorts): row*72 + 16*(row>>2). Row starts 16B-aligned;
// 4-row group stride = 152 dw === 24 (mod 32); P b64 writes and A b128 reads
// enumerate to the 32-bank minimum (4 dw/bank = 512 B floor per wave op).
__device__ __forceinline__ int ldsoff(int row) {
  return row * 72 + 16 * (row >> 2);
}
#define LDS_SZ (64 * 72 + 16 * 16)   // shorts; 9728 B (P band only)

// ---- exact JAX *partitionable* threefry2x32, key = PRNGKey(42) -> (0, 42) ----
// counter = (0, f) since total 2^26 < 2^32; output word = out0 ^ out1.
__device__ __forceinline__ unsigned tf_bits(unsigned f) {
  unsigned x0 = 0u;
  unsigned x1 = f;
  const unsigned ks1 = 42u;
  const unsigned ks2 = 0x1BD11BDAu ^ 42u;
  x1 += ks1;                       // x0 += ks0 (=0)
#define TF_R(r) { x0 += x1; x1 = __builtin_amdgcn_alignbit(x1, x1, 32u - (r)); x1 ^= x0; }
  TF_R(13) TF_R(15) TF_R(26) TF_R(6)
  x0 += ks1; x1 += ks2 + 1u;
  TF_R(17) TF_R(29) TF_R(16) TF_R(24)
  x0 += ks2; x1 += 2u;             // + ks0 + 2
  TF_R(13) TF_R(15) TF_R(26) TF_R(6)
  x1 += ks1 + 3u;                  // x0 += ks0 (=0)
  TF_R(17) TF_R(29) TF_R(16) TF_R(24)
  x0 += ks1; x1 += ks2 + 4u;
  TF_R(13) TF_R(15) TF_R(26) TF_R(6)
  x0 += ks2; x1 += 5u;             // + ks0 + 5
#undef TF_R
  return x0 ^ x1;
}
// keep <=> uniform(bits) < 0.9f <=> bits < 0xE6666600
#define KEEP_THRESH 0xE6666600u

__device__ __forceinline__ unsigned pack_bf16x2(float lo, float hi) {
  const unsigned l = (__float_as_uint(lo) + 0x8000u) >> 16;
  const unsigned h = (__float_as_uint(hi) + 0x8000u) & 0xFFFF0000u;
  return h | l;
}

// ws layout (32-bit words):
//  [0, 1048576)        K_frag: QK^T B-fragments, bf16-packed
//  [1048576, 2097152)  V_frag: PV  B-fragments, bf16-packed
//  [2097152, 2129920)  l sums (fp32, atomically accumulated)
// total 8,519,680 B <= 8,650,752 B (budget proven available R7-R9)
#define WS_KF 0
#define WS_VF 1048576
#define WS_L  2097152

// Fragment entry index: e = (((b*32 + kt)*4 + nt)*2 + ks)*64 + lane, 16 B each.
// K_frag[e] = K[b][kt*64 + 4*tx + nt][ks*32 + quad*8 .. +7]   (tx=lane&15, quad=lane>>4)
//   -> S column (nt,tx) = key 4*tx+nt: lane's 4 mask cols {4tx..4tx+3} = ONE
//      int4 load; P columns become identity (one b64 write per row).
// V_frag[e] = V[b][kt*64 + ks*32 + quad*8 + j][nt*16 + tx], j=0..7
//   -> exact PV B-fragment for identity P columns.
__global__ __launch_bounds__(NTHREADS)
void convert_kv(const float* __restrict__ k, const float* __restrict__ v,
                unsigned* __restrict__ ws) {
  const unsigned gid = blockIdx.x * NTHREADS + threadIdx.x;
  const unsigned e = gid & 262143u;
  const int lane = e & 63;
  const int ks = (e >> 6) & 1, nt = (e >> 7) & 3, kt = (e >> 9) & 31, b = e >> 14;
  const int tx = lane & 15, quad = lane >> 4;
  uint4 wout;
  if (gid < 262144u) {
    // R10 BUG WAS HERE: missing ks*32 -> stored d[0:32) twice, never d[32:64)
    const float* src = k + ((size_t)b * SEQ + kt * 64 + 4 * tx + nt) * DIM
                         + ks * 32 + quad * 8;
    const float4 f0 = *(const float4*)src;
    const float4 f1 = *(const float4*)(src + 4);
    wout.x = pack_bf16x2(f0.x, f0.y); wout.y = pack_bf16x2(f0.z, f0.w);
    wout.z = pack_bf16x2(f1.x, f1.y); wout.w = pack_bf16x2(f1.z, f1.w);
    *(uint4*)(ws + WS_KF + (size_t)e * 4) = wout;
  } else {
    const float* src = v + ((size_t)b * SEQ + kt * 64 + ks * 32 + quad * 8) * DIM
                         + nt * 16 + tx;
    const float a0 = src[0 * DIM], a1 = src[1 * DIM], a2 = src[2 * DIM], a3 = src[3 * DIM];
    const float a4 = src[4 * DIM], a5 = src[5 * DIM], a6 = src[6 * DIM], a7 = src[7 * DIM];
    wout.x = pack_bf16x2(a0, a1); wout.y = pack_bf16x2(a2, a3);
    wout.z = pack_bf16x2(a4, a5); wout.w = pack_bf16x2(a6, a7);
    *(uint4*)(ws + WS_VF + (size_t)e * 4) = wout;
  }
}

// Barrier-free flash attention, split-K x2 via atomic numerator accumulation.
// All K/V come from pre-converted fragment buffers (pure 16B coalesced loads,
// no conversion VALU, no LDS staging, no __syncthreads). Only the wave-private
// P C-layout -> A-layout transpose uses LDS (same-wave DS ordering).
__global__ __launch_bounds__(NTHREADS, 4)
void attn_fwd(const float* __restrict__ q, const unsigned* __restrict__ ws,
              const int* __restrict__ mask, float* __restrict__ out,
              float* __restrict__ lsum) {
  __shared__ unsigned short PS[LDS_SZ];

  const int t    = threadIdx.x;
  const int w    = t >> 6;
  const int lane = t & 63;
  const int tx   = lane & 15;
  const int quad = lane >> 4;

  int bid = blockIdx.x;
  const int half = bid >> 9;
  bid &= 511;
  const int bb = bid >> 5;
  const int q0 = (bid & 31) * 64;
  const int qw = q0 + 16 * w;
  const int kt0 = half * 16;

  // fold 1/sqrt(64) and log2(e) into Q: softmax in exp2 domain; fixed-max
  // (scores ~ N(0,1.44^2), max over 2^26 ~ 8.4 -> exp2 never overflows)
  const float qscale = 0.125f * 1.44269504088896340736f;

  bf16x8 aq[2];
  {
    const float* qr = q + ((size_t)bb * SEQ + qw + tx) * DIM + quad * 8;
#pragma unroll
    for (int ks = 0; ks < 2; ++ks) {
      const float4 f0 = *(const float4*)(qr + ks * 32);
      const float4 f1 = *(const float4*)(qr + ks * 32 + 4);
      union { unsigned u[4]; bf16x8 v; } a;
      a.u[0] = pack_bf16x2(f0.x * qscale, f0.y * qscale);
      a.u[1] = pack_bf16x2(f0.z * qscale, f0.w * qscale);
      a.u[2] = pack_bf16x2(f1.x * qscale, f1.y * qscale);
      a.u[3] = pack_bf16x2(f1.z * qscale, f1.w * qscale);
      aq[ks] = a.v;
    }
  }

  float lrun[4] = {0.f, 0.f, 0.f, 0.f};
  f32x4 oacc[4];
#pragma unroll
  for (int nt = 0; nt < 4; ++nt) oacc[nt] = (f32x4){0.f, 0.f, 0.f, 0.f};

  // per-kt fragment block = 2048 words (8192 B)
  const unsigned* kfb = ws + WS_KF + (size_t)(bb * 32) * 2048 + (size_t)lane * 4;
  const unsigned* vfb = ws + WS_VF + (size_t)(bb * 32) * 2048 + (size_t)lane * 4;
  const int* mbase = mask + (size_t)(qw + quad * 4) * SEQ + 4 * tx;
  const unsigned fbase0 = (unsigned)(bb * SEQ + qw + quad * 4) * (unsigned)SEQ
                          + (unsigned)(4 * tx);

#pragma unroll 1
  for (int kt = kt0; kt < kt0 + 16; ++kt) {
    const int k0 = kt * 64;

    // ---- mask rows: ONE int4 per reg (keys 4tx..4tx+3) ----
    int4 mv[4];
#pragma unroll
    for (int reg = 0; reg < 4; ++reg)
      mv[reg] = *(const int4*)(mbase + (size_t)reg * SEQ + k0);

    // ---- K fragments direct from global (L2/L3-resident) ----
    const unsigned* kfp = kfb + (size_t)kt * 2048;
    bf16x8 kf[4][2];
#pragma unroll
    for (int nt = 0; nt < 4; ++nt)
#pragma unroll
      for (int ks = 0; ks < 2; ++ks)
        kf[nt][ks] = *(const bf16x8*)(kfp + (nt * 2 + ks) * 256);

    // ---- S = Q K^T ----
    f32x4 qk[4];
#pragma unroll
    for (int nt = 0; nt < 4; ++nt) {
      f32x4 c = (f32x4){0.f, 0.f, 0.f, 0.f};
#pragma unroll
      for (int ks = 0; ks < 2; ++ks)
        c = __builtin_amdgcn_mfma_f32_16x16x32_bf16(aq[ks], kf[nt][ks], c, 0, 0, 0);
      qk[nt] = c;
    }

    // ---- V fragments: issue now, consumed after the long RNG phase ----
    const unsigned* vfp = vfb + (size_t)kt * 2048;
    bf16x8 vf[4][2];
#pragma unroll
    for (int nt = 0; nt < 4; ++nt)
#pragma unroll
      for (int ks = 0; ks < 2; ++ks)
        vf[nt][ks] = *(const bf16x8*)(vfp + (nt * 2 + ks) * 256);

    // ---- exp2 + dropout + l partials; P -> wave-private LDS (identity cols) ----
    const unsigned fb = fbase0 + (unsigned)k0;
#pragma unroll
    for (int reg = 0; reg < 4; ++reg) {
      const int* mreg = (const int*)&mv[reg];
      float pd[4];
      float ls = 0.0f;
#pragma unroll
      for (int nt = 0; nt < 4; ++nt) {
        const float s = mreg[nt] ? qk[nt][reg] : -1e30f;
        const float e = __builtin_amdgcn_exp2f(s);        // masked -> +0
        ls += e;
        const unsigned bits = tf_bits(fb + (unsigned)(reg * SEQ) + (unsigned)nt);
        pd[nt] = (bits < KEEP_THRESH) ? e : 0.0f;         // 1/0.9 folded in combine
      }
      lrun[reg] += ls;
      uint2 pw;
      pw.x = pack_bf16x2(pd[0], pd[1]);
      pw.y = pack_bf16x2(pd[2], pd[3]);
      *(uint2*)&PS[ldsoff(16 * w + quad * 4 + reg) + 4 * tx] = pw;
    }

    // ---- O += P V ----
#pragma unroll
    for (int ks = 0; ks < 2; ++ks) {
      const bf16x8 ap = *(const bf16x8*)&PS[ldsoff(16 * w + tx) + ks * 32 + quad * 8];
#pragma unroll
      for (int nt = 0; nt < 4; ++nt)
        oacc[nt] = __builtin_amdgcn_mfma_f32_16x16x32_bf16(ap, vf[nt][ks], oacc[nt], 0, 0, 0);
    }
  }

  // ---- epilogue: l reduce + atomic accumulate (out zeroed by host memset) ----
  float lred[4];
#pragma unroll
  for (int reg = 0; reg < 4; ++reg) {
    float ls = lrun[reg];
    ls += __shfl_xor(ls, 1);
    ls += __shfl_xor(ls, 2);
    ls += __shfl_xor(ls, 4);
    ls += __shfl_xor(ls, 8);
    lred[reg] = ls;
  }
  if (tx == 0) {
#pragma unroll
    for (int reg = 0; reg < 4; ++reg)
      atomicAdd(&lsum[bb * SEQ + qw + quad * 4 + reg], lred[reg]);
  }
  float* ob = out + ((size_t)bb * SEQ + qw) * DIM;
#pragma unroll
  for (int nt = 0; nt < 4; ++nt)
#pragma unroll
    for (int reg = 0; reg < 4; ++reg)
      atomicAdd(&ob[(size_t)(quad * 4 + reg) * DIM + nt * 16 + tx], oacc[nt][reg]);
}

// out = numerator / (0.9 * l)   (dropout scale folded here)
__global__ __launch_bounds__(NTHREADS)
void combine(float* __restrict__ out, const float* __restrict__ lsum) {
  const int gid = blockIdx.x * NTHREADS + threadIdx.x;
  const int row = gid >> 6;                  // wave-uniform -> scalar load
  out[gid] = out[gid] * (1.0f / (0.9f * lsum[row]));
}

extern "C" void kernel_launch(void* const* d_in, const int* in_sizes, int n_in,
                              void* d_out, int out_size, void* d_ws, size_t ws_size,
                              hipStream_t stream) {
  const float* q = (const float*)d_in[0];
  const float* k = (const float*)d_in[1];
  const float* v = (const float*)d_in[2];
  const int* mask = (const int*)d_in[3];
  float* out = (float*)d_out;
  unsigned* ws = (unsigned*)d_ws;

  hipMemsetAsync(out, 0, (size_t)out_size * 4, stream);
  hipMemsetAsync((float*)d_ws + WS_L, 0, (size_t)NROWS * 4, stream);
  hipLaunchKernelGGL(convert_kv, dim3(2048), dim3(NTHREADS), 0, stream, k, v, ws);
  hipLaunchKernelGGL(attn_fwd, dim3(1024), dim3(NTHREADS), 0, stream,
                     q, ws, mask, out, (float*)d_ws + WS_L);
  hipLaunchKernelGGL(combine, dim3(OUTELEMS / NTHREADS), dim3(NTHREADS), 0, stream,
                     out, (const float*)d_ws + WS_L);
}

// Round 12
// 231.110 us; speedup vs baseline: 1.0521x; 1.0521x over previous
//
#include <hip/hip_runtime.h>

#define BATCH 16
#define SEQ   2048
#define DIM   64
#define NTHREADS 256
#define NROWS    (BATCH * SEQ)      // 32768
#define OUTELEMS (NROWS * DIM)      // 2097152

typedef short bf16x8 __attribute__((ext_vector_type(8)));
typedef float f32x4 __attribute__((ext_vector_type(4)));

// LDS row offset (shorts): row*72 + 16*(row>>2). Row starts 16B-aligned;
// 4-row group stride = 152 dw === 24 (mod 32); P b64 writes and A b128 reads
// enumerate to the 32-bank minimum.
__device__ __forceinline__ int ldsoff(int row) {
  return row * 72 + 16 * (row >> 2);
}
#define LDS_SZ (64 * 72 + 16 * 16)   // shorts; 9728 B (wave-private P bands)

// ---- exact JAX *partitionable* threefry2x32, key = PRNGKey(42) -> (0, 42) ----
// counter = (0, f) since total 2^26 < 2^32; output word = out0 ^ out1.
__device__ __forceinline__ unsigned tf_bits(unsigned f) {
  unsigned x0 = 0u;
  unsigned x1 = f;
  const unsigned ks1 = 42u;
  const unsigned ks2 = 0x1BD11BDAu ^ 42u;
  x1 += ks1;                       // x0 += ks0 (=0)
#define TF_R(r) { x0 += x1; x1 = __builtin_amdgcn_alignbit(x1, x1, 32u - (r)); x1 ^= x0; }
  TF_R(13) TF_R(15) TF_R(26) TF_R(6)
  x0 += ks1; x1 += ks2 + 1u;
  TF_R(17) TF_R(29) TF_R(16) TF_R(24)
  x0 += ks2; x1 += 2u;             // + ks0 + 2
  TF_R(13) TF_R(15) TF_R(26) TF_R(6)
  x1 += ks1 + 3u;                  // x0 += ks0 (=0)
  TF_R(17) TF_R(29) TF_R(16) TF_R(24)
  x0 += ks1; x1 += ks2 + 4u;
  TF_R(13) TF_R(15) TF_R(26) TF_R(6)
  x0 += ks2; x1 += 5u;             // + ks0 + 5
#undef TF_R
  return x0 ^ x1;
}
// keep <=> uniform(bits) < 0.9f <=> bits < 0xE6666600
#define KEEP_THRESH 0xE6666600u

__device__ __forceinline__ unsigned pack_bf16x2(float lo, float hi) {   // round-half-up
  const unsigned l = (__float_as_uint(lo) + 0x8000u) >> 16;
  const unsigned h = (__float_as_uint(hi) + 0x8000u) & 0xFFFF0000u;
  return h | l;
}
// truncating bf16x2 pack: single v_perm_b32 (P values only; <=0.4% rel err)
__device__ __forceinline__ unsigned pack_trunc(float lo, float hi) {
  return __builtin_amdgcn_perm(__float_as_uint(hi), __float_as_uint(lo), 0x07060302u);
}

// ws layout (32-bit words): K_frag [0,1048576) | V_frag [1048576,2097152). 8 MB.
#define WS_KF 0
#define WS_VF 1048576

// Fragment entry index: e = (((b*32 + kt)*4 + nt)*2 + ks)*64 + lane, 16 B each.
// K_frag[e] = K[b][kt*64 + 4*tx + nt][ks*32 + quad*8 .. +7]
// V_frag[e] = V[b][kt*64 + ks*32 + quad*8 + j][nt*16 + tx], j=0..7
__global__ __launch_bounds__(NTHREADS)
void convert_kv(const float* __restrict__ k, const float* __restrict__ v,
                unsigned* __restrict__ ws) {
  const unsigned gid = blockIdx.x * NTHREADS + threadIdx.x;
  const unsigned e = gid & 262143u;
  const int lane = e & 63;
  const int ks = (e >> 6) & 1, nt = (e >> 7) & 3, kt = (e >> 9) & 31, b = e >> 14;
  const int tx = lane & 15, quad = lane >> 4;
  uint4 wout;
  if (gid < 262144u) {
    const float* src = k + ((size_t)b * SEQ + kt * 64 + 4 * tx + nt) * DIM
                         + ks * 32 + quad * 8;
    const float4 f0 = *(const float4*)src;
    const float4 f1 = *(const float4*)(src + 4);
    wout.x = pack_bf16x2(f0.x, f0.y); wout.y = pack_bf16x2(f0.z, f0.w);
    wout.z = pack_bf16x2(f1.x, f1.y); wout.w = pack_bf16x2(f1.z, f1.w);
    *(uint4*)(ws + WS_KF + (size_t)e * 4) = wout;
  } else {
    const float* src = v + ((size_t)b * SEQ + kt * 64 + ks * 32 + quad * 8) * DIM
                         + nt * 16 + tx;
    const float a0 = src[0 * DIM], a1 = src[1 * DIM], a2 = src[2 * DIM], a3 = src[3 * DIM];
    const float a4 = src[4 * DIM], a5 = src[5 * DIM], a6 = src[6 * DIM], a7 = src[7 * DIM];
    wout.x = pack_bf16x2(a0, a1); wout.y = pack_bf16x2(a2, a3);
    wout.z = pack_bf16x2(a4, a5); wout.w = pack_bf16x2(a6, a7);
    *(uint4*)(ws + WS_VF + (size_t)e * 4) = wout;
  }
}

// Barrier-free flash attention, software-pipelined:
//   iter kt: [issue kf(kt)/vf(kt)/mask(kt) loads] -> PV(kt-1) (P ds_read far
//   from its write; vf(kt-1) register-resident since last iter) -> QK(kt)
//   (kf drains under PV) -> RNG(kt) (vf(kt) drains underneath) -> P(kt) write.
// V-fragment registers double-buffered via 2x-unrolled loop (no copy movs).
// No split-K: full 2048 keys/wave, direct normalized store, no atomics.
__global__ __launch_bounds__(NTHREADS, 2)
void attn_fwd(const float* __restrict__ q, const unsigned* __restrict__ ws,
              const int* __restrict__ mask, float* __restrict__ out) {
  __shared__ unsigned short PS[LDS_SZ];

  const int t    = threadIdx.x;
  const int w    = t >> 6;
  const int lane = t & 63;
  const int tx   = lane & 15;
  const int quad = lane >> 4;

  const int bb = blockIdx.x >> 5;
  const int q0 = (blockIdx.x & 31) * 64;
  const int qw = q0 + 16 * w;

  // fold 1/sqrt(64) and log2(e) into Q: softmax in exp2 domain; fixed-max
  // (scores ~ N(0,1.44^2), max over 2^26 ~ 8.4 -> exp2 never overflows)
  const float qscale = 0.125f * 1.44269504088896340736f;

  bf16x8 aq[2];
  {
    const float* qr = q + ((size_t)bb * SEQ + qw + tx) * DIM + quad * 8;
#pragma unroll
    for (int ks = 0; ks < 2; ++ks) {
      const float4 f0 = *(const float4*)(qr + ks * 32);
      const float4 f1 = *(const float4*)(qr + ks * 32 + 4);
      union { unsigned u[4]; bf16x8 v; } a;
      a.u[0] = pack_bf16x2(f0.x * qscale, f0.y * qscale);
      a.u[1] = pack_bf16x2(f0.z * qscale, f0.w * qscale);
      a.u[2] = pack_bf16x2(f1.x * qscale, f1.y * qscale);
      a.u[3] = pack_bf16x2(f1.z * qscale, f1.w * qscale);
      aq[ks] = a.v;
    }
  }

  float lrun[4] = {0.f, 0.f, 0.f, 0.f};
  f32x4 oacc[4];
#pragma unroll
  for (int nt = 0; nt < 4; ++nt) oacc[nt] = (f32x4){0.f, 0.f, 0.f, 0.f};

  const unsigned* kfb = ws + WS_KF + (size_t)(bb * 32) * 2048 + (size_t)lane * 4;
  const unsigned* vfb = ws + WS_VF + (size_t)(bb * 32) * 2048 + (size_t)lane * 4;
  const int* mbase = mask + (size_t)(qw + quad * 4) * SEQ + 4 * tx;
  const unsigned fbase0 = (unsigned)(bb * SEQ + qw + quad * 4) * (unsigned)SEQ
                          + (unsigned)(4 * tx);

  bf16x8 vfA[4][2], vfB[4][2];

  // ---- RNG + P-write block (tile kt, scores in qk) ----
#define RNG_PWRITE(kt_, qk_)                                                   \
  {                                                                            \
    const unsigned fb = fbase0 + (unsigned)((kt_) * 64);                       \
    _Pragma("unroll")                                                          \
    for (int reg = 0; reg < 4; ++reg) {                                        \
      const int* mreg = (const int*)&mv[reg];                                  \
      float pd[4];                                                             \
      float ls = 0.0f;                                                         \
      _Pragma("unroll")                                                        \
      for (int nt = 0; nt < 4; ++nt) {                                         \
        const float s = mreg[nt] ? qk_[nt][reg] : -1e30f;                      \
        const float e = __builtin_amdgcn_exp2f(s);                             \
        ls += e;                                                               \
        const unsigned bits = tf_bits(fb + (unsigned)(reg * SEQ) + (unsigned)nt); \
        pd[nt] = (bits < KEEP_THRESH) ? e : 0.0f;                              \
      }                                                                        \
      lrun[reg] += ls;                                                         \
      uint2 pw;                                                                \
      pw.x = pack_trunc(pd[0], pd[1]);                                         \
      pw.y = pack_trunc(pd[2], pd[3]);                                         \
      *(uint2*)&PS[ldsoff(16 * w + quad * 4 + reg) + 4 * tx] = pw;             \
    }                                                                          \
  }

  // ---- prologue: tile 0 (no PV yet) ----
  {
    const unsigned* kfp = kfb;
    const unsigned* vfp = vfb;
    bf16x8 kf[4][2];
#pragma unroll
    for (int nt = 0; nt < 4; ++nt)
#pragma unroll
      for (int ks = 0; ks < 2; ++ks) {
        kf[nt][ks]  = *(const bf16x8*)(kfp + (nt * 2 + ks) * 256);
        vfA[nt][ks] = *(const bf16x8*)(vfp + (nt * 2 + ks) * 256);
      }
    int4 mv[4];
#pragma unroll
    for (int reg = 0; reg < 4; ++reg)
      mv[reg] = *(const int4*)(mbase + (size_t)reg * SEQ);
    f32x4 qk[4];
#pragma unroll
    for (int nt = 0; nt < 4; ++nt) {
      f32x4 c = (f32x4){0.f, 0.f, 0.f, 0.f};
#pragma unroll
      for (int ks = 0; ks < 2; ++ks)
        c = __builtin_amdgcn_mfma_f32_16x16x32_bf16(aq[ks], kf[nt][ks], c, 0, 0, 0);
      qk[nt] = c;
    }
    RNG_PWRITE(0, qk)
  }

  // ---- pipelined body: loads(kt) -> PV(kt-1) -> QK(kt) -> RNG(kt)+Pwrite ----
#define BODY(kt_, prevV, curV)                                                 \
  {                                                                            \
    const unsigned* kfp = kfb + (size_t)(kt_) * 2048;                          \
    const unsigned* vfp = vfb + (size_t)(kt_) * 2048;                          \
    bf16x8 kf[4][2];                                                           \
    _Pragma("unroll")                                                          \
    for (int nt = 0; nt < 4; ++nt)                                             \
      _Pragma("unroll")                                                        \
      for (int ks = 0; ks < 2; ++ks) {                                         \
        kf[nt][ks]   = *(const bf16x8*)(kfp + (nt * 2 + ks) * 256);            \
        curV[nt][ks] = *(const bf16x8*)(vfp + (nt * 2 + ks) * 256);            \
      }                                                                        \
    int4 mv[4];                                                                \
    _Pragma("unroll")                                                          \
    for (int reg = 0; reg < 4; ++reg)                                          \
      mv[reg] = *(const int4*)(mbase + (size_t)reg * SEQ + (kt_) * 64);        \
    _Pragma("unroll")                                                          \
    for (int ks = 0; ks < 2; ++ks) {                                           \
      const bf16x8 ap = *(const bf16x8*)&PS[ldsoff(16 * w + tx) + ks * 32 + quad * 8]; \
      _Pragma("unroll")                                                        \
      for (int nt = 0; nt < 4; ++nt)                                           \
        oacc[nt] = __builtin_amdgcn_mfma_f32_16x16x32_bf16(ap, prevV[nt][ks],  \
                                                           oacc[nt], 0, 0, 0); \
    }                                                                          \
    f32x4 qk[4];                                                               \
    _Pragma("unroll")                                                          \
    for (int nt = 0; nt < 4; ++nt) {                                           \
      f32x4 c = (f32x4){0.f, 0.f, 0.f, 0.f};                                   \
      _Pragma("unroll")                                                        \
      for (int ks = 0; ks < 2; ++ks)                                           \
        c = __builtin_amdgcn_mfma_f32_16x16x32_bf16(aq[ks], kf[nt][ks], c, 0, 0, 0); \
      qk[nt] = c;                                                              \
    }                                                                          \
    RNG_PWRITE(kt_, qk)                                                        \
  }

#pragma unroll 1
  for (int kt = 1; kt < 31; kt += 2) {
    BODY(kt, vfA, vfB)
    BODY(kt + 1, vfB, vfA)
  }
  BODY(31, vfA, vfB)

  // ---- final PV(31) ----
#pragma unroll
  for (int ks = 0; ks < 2; ++ks) {
    const bf16x8 ap = *(const bf16x8*)&PS[ldsoff(16 * w + tx) + ks * 32 + quad * 8];
#pragma unroll
    for (int nt = 0; nt < 4; ++nt)
      oacc[nt] = __builtin_amdgcn_mfma_f32_16x16x32_bf16(ap, vfB[nt][ks], oacc[nt], 0, 0, 0);
  }

  // ---- epilogue: l reduce, normalize (dropout 1/0.9 folded), store ----
  float linv[4];
#pragma unroll
  for (int reg = 0; reg < 4; ++reg) {
    float ls = lrun[reg];
    ls += __shfl_xor(ls, 1);
    ls += __shfl_xor(ls, 2);
    ls += __shfl_xor(ls, 4);
    ls += __shfl_xor(ls, 8);
    linv[reg] = (1.0f / 0.9f) / ls;
  }
  float* ob = out + ((size_t)bb * SEQ + qw) * DIM;
#pragma unroll
  for (int nt = 0; nt < 4; ++nt)
#pragma unroll
    for (int reg = 0; reg < 4; ++reg)
      ob[(size_t)(quad * 4 + reg) * DIM + nt * 16 + tx] = oacc[nt][reg] * linv[reg];
}

extern "C" void kernel_launch(void* const* d_in, const int* in_sizes, int n_in,
                              void* d_out, int out_size, void* d_ws, size_t ws_size,
                              hipStream_t stream) {
  const float* q = (const float*)d_in[0];
  const float* k = (const float*)d_in[1];
  const float* v = (const float*)d_in[2];
  const int* mask = (const int*)d_in[3];
  float* out = (float*)d_out;
  unsigned* ws = (unsigned*)d_ws;

  hipLaunchKernelGGL(convert_kv, dim3(2048), dim3(NTHREADS), 0, stream, k, v, ws);
  hipLaunchKernelGGL(attn_fwd, dim3(512), dim3(NTHREADS), 0, stream,
                     q, ws, mask, out);
}